// Round 1
// baseline (981.466 us; speedup 1.0000x reference)
//
#include <hip/hip_runtime.h>

#define DH 128

typedef float  floatx4 __attribute__((ext_vector_type(4)));
typedef short  shortx8 __attribute__((ext_vector_type(8)));

__device__ __forceinline__ unsigned short f2bf(float f) {
    unsigned u = __builtin_bit_cast(unsigned, f);
    u += 0x7fffu + ((u >> 16) & 1u);
    return (unsigned short)(u >> 16);
}
__device__ __forceinline__ float bf2f(unsigned short h) {
    unsigned u = ((unsigned)h) << 16;
    return __builtin_bit_cast(float, u);
}
__device__ __forceinline__ float silu_f(float x) { return x / (1.f + expf(-x)); }

// ---------------- weight prep: [L][K][128] f32 -> [L][128][KP] bf16 (zero-pad K..KP) ----------------
__global__ void prep_w_kernel(const float* __restrict__ src, unsigned short* __restrict__ dst,
                              int L, int K, int KP) {
    int idx = blockIdx.x * 256 + threadIdx.x;
    int tot = L * 128 * KP;
    if (idx >= tot) return;
    int l = idx / (128 * KP);
    int rem = idx - l * 128 * KP;
    int n = rem / KP;
    int k = rem - n * KP;
    float v = (k < K) ? src[(size_t)l * K * 128 + (size_t)k * 128 + n] : 0.f;
    dst[idx] = f2bf(v);
}

// ---------------- node encoder: h = silu(x@w1+b1)@w2+b2 ; 16 nodes per 128-thread block ----------------
__global__ __launch_bounds__(128)
void node_enc_kernel(const float* __restrict__ xyr,
                     const float* __restrict__ w1, const float* __restrict__ b1,
                     const float* __restrict__ w2, const float* __restrict__ b2,
                     float* __restrict__ h, unsigned short* __restrict__ hbf, int N) {
    __shared__ float xs[16][3];
    __shared__ float hid[16][DH];
    int n0 = blockIdx.x * 16;
    int t = threadIdx.x;
    if (t < 48) {
        int i = t / 3, j = t - 3 * (t / 3);
        int n = n0 + i; if (n >= N) n = N - 1;
        xs[i][j] = xyr[3 * n + j];
    }
    __syncthreads();
    int col = t;
    float w10 = w1[col], w11 = w1[DH + col], w12 = w1[2 * DH + col];
    float bb = b1[col];
#pragma unroll
    for (int i = 0; i < 16; ++i) {
        float v = bb + xs[i][0] * w10 + xs[i][1] * w11 + xs[i][2] * w12;
        hid[i][col] = silu_f(v);
    }
    __syncthreads();
    float a[16];
#pragma unroll
    for (int i = 0; i < 16; ++i) a[i] = b2[col];
    for (int j = 0; j < DH; ++j) {
        float wv = w2[j * DH + col];
#pragma unroll
        for (int i = 0; i < 16; ++i) a[i] += hid[i][j] * wv;
    }
    for (int i = 0; i < 16; ++i) {
        int n = n0 + i;
        if (n < N) {
            h[(size_t)n * DH + col] = a[i];
            hbf[(size_t)n * DH + col] = f2bf(a[i]);
        }
    }
}

// ---------------- RBF per edge -> bf16 [E][16] ----------------
__global__ void rbf_kernel(const float* __restrict__ xyr, const int* __restrict__ src,
                           const int* __restrict__ dst, unsigned short* __restrict__ rbfbf, int E) {
    int e = blockIdx.x * 256 + threadIdx.x;
    if (e >= E) return;
    int s = src[e], d = dst[e];
    float dx = xyr[3 * s] - xyr[3 * d];
    float dy = xyr[3 * s + 1] - xyr[3 * d + 1];
    float r = sqrtf(dx * dx + dy * dy + 1e-8f);
    const float step = 1.41421356237309515f / 15.f;
    const float gamma = 56.25f;
    unsigned out[8];
#pragma unroll
    for (int i = 0; i < 8; ++i) {
        float c0 = (2 * i) * step, c1 = (2 * i + 1) * step;
        float d0 = r - c0, d1 = r - c1;
        out[i] = (unsigned)f2bf(expf(-gamma * d0 * d0)) |
                 ((unsigned)f2bf(expf(-gamma * d1 * d1)) << 16);
    }
    uint4* p = (uint4*)(rbfbf + (size_t)e * 16);
    p[0] = make_uint4(out[0], out[1], out[2], out[3]);
    p[1] = make_uint4(out[4], out[5], out[6], out[7]);
}

// ---------------- CSR build ----------------
__global__ void count_kernel(const int* __restrict__ dst, int* __restrict__ cnt, int E) {
    int e = blockIdx.x * 256 + threadIdx.x;
    if (e < E) atomicAdd(&cnt[dst[e]], 1);
}
__global__ __launch_bounds__(1024)
void scan_kernel(const int* __restrict__ cnt, int* __restrict__ rs, int* __restrict__ cursor, int N) {
    __shared__ int ps[1024];
    const int CH = 16;
    int t = threadIdx.x;
    int base = t * CH;
    int loc[CH];
    int s = 0;
#pragma unroll
    for (int j = 0; j < CH; ++j) {
        int i = base + j;
        int v = (i < N) ? cnt[i] : 0;
        loc[j] = s; s += v;
    }
    ps[t] = s;
    __syncthreads();
    for (int off = 1; off < 1024; off <<= 1) {
        int v = (t >= off) ? ps[t - off] : 0;
        __syncthreads();
        ps[t] += v;
        __syncthreads();
    }
    int pre = (t > 0) ? ps[t - 1] : 0;
#pragma unroll
    for (int j = 0; j < CH; ++j) {
        int i = base + j;
        if (i < N) { int v = pre + loc[j]; rs[i] = v; cursor[i] = v; }
    }
    if (t == 0) rs[N] = ps[1023];
}
__global__ void fill_kernel(const int* __restrict__ dst, int* __restrict__ cursor,
                            int* __restrict__ eids, int E) {
    int e = blockIdx.x * 256 + threadIdx.x;
    if (e < E) {
        int p = atomicAdd(&cursor[dst[e]], 1);
        eids[p] = e;
    }
}

// ---------------- CSR gather-sum: agg_bf[n][c] = sum over incident edges of m_bf ----------------
__global__ __launch_bounds__(128)
void agg_kernel(const unsigned short* __restrict__ mbuf, const int* __restrict__ rs,
                const int* __restrict__ eids, unsigned short* __restrict__ aggbf, int N) {
    int n = blockIdx.x;
    int c = threadIdx.x;
    int s = rs[n], e = rs[n + 1];
    float acc = 0.f;
    for (int j = s; j < e; ++j) acc += bf2f(mbuf[(size_t)eids[j] * DH + c]);
    aggbf[(size_t)n * DH + c] = f2bf(acc);
}

// ---------------- residual + layernorm, emits f32 h and bf16 h ----------------
__global__ __launch_bounds__(128)
void ln_kernel(float* __restrict__ h, const float* __restrict__ hup,
               const float* __restrict__ g, const float* __restrict__ b,
               unsigned short* __restrict__ hbf, int N) {
    int n = blockIdx.x, c = threadIdx.x;
    float x = h[(size_t)n * DH + c] + hup[(size_t)n * DH + c];
    float s1 = x, s2 = x * x;
#pragma unroll
    for (int o = 32; o > 0; o >>= 1) {
        s1 += __shfl_xor(s1, o);
        s2 += __shfl_xor(s2, o);
    }
    __shared__ float r1[2], r2[2];
    int lane = c & 63, wd = c >> 6;
    if (lane == 0) { r1[wd] = s1; r2[wd] = s2; }
    __syncthreads();
    float mu = (r1[0] + r1[1]) * (1.f / DH);
    float var = (r2[0] + r2[1]) * (1.f / DH) - mu * mu;
    float y = (x - mu) * rsqrtf(var + 1e-5f) * g[c] + b[c];
    h[(size_t)n * DH + c] = y;
    hbf[(size_t)n * DH + c] = f2bf(y);
}

// ---------------- fused 2-layer MLP over 64-row tiles, bf16 MFMA ----------------
// MODE 0: edge msg  (gather h[src],h[dst],rbf; K1=272->288; out: m_bf [E][128])
// MODE 1: node upd  (rows = [hbf | aggbf];     K1=256;      out: hup f32 [N][128])
// MODE 2: pair head (gather h[u],h[v],rpair;   K1=260->288; out: logits f32 [P], GEMM2 replaced by dot)
template<int MODE, int KC1>
__global__ __launch_bounds__(256)
void mlp2_kernel(const unsigned short* __restrict__ hbf,
                 const unsigned short* __restrict__ aux,   // MODE0: rbfbf ; MODE1: aggbf
                 const int* __restrict__ idxA,             // MODE0: src ; MODE2: pairs (u,v interleaved)
                 const int* __restrict__ idxB,             // MODE0: dst
                 const float* __restrict__ xyr,            // MODE2
                 const unsigned short* __restrict__ W1T,   // [128][KC1*32] bf16
                 const float* __restrict__ b1,
                 const unsigned short* __restrict__ W2T,   // [128][128] bf16 (MODE0/1)
                 const float* __restrict__ b2,             // MODE2: eh_b2 scalar
                 const float* __restrict__ w2f,            // MODE2: eh_w2 [128] f32
                 unsigned short* __restrict__ out_bf,      // MODE0
                 float* __restrict__ out_f,                // MODE1 / MODE2
                 int M) {
    constexpr int K1B = KC1 * 32;      // W1T row stride
    constexpr int K1P = K1B + 8;       // LDS A row stride (16B aligned, bank-balanced)
    constexpr int HP  = DH + 8;        // 136: LDS hidden row stride
    __shared__ unsigned short A1[64 * K1P];
    __shared__ unsigned short HID[64 * HP];
    __shared__ int SIDX[64], DIDX[64];

    const int tid = threadIdx.x;
    const int row0 = blockIdx.x * 64;

    if (MODE != 1) {
        if (tid < 64) {
            int e = row0 + tid;
            if (e >= M) e = M - 1;
            if (MODE == 0) { SIDX[tid] = idxA[e]; DIDX[tid] = idxB[e]; }
            else           { SIDX[tid] = idxA[2 * e]; DIDX[tid] = idxA[2 * e + 1]; }
        }
        __syncthreads();
    }

    // ---- gather rows into LDS (16B chunks of 8 bf16) ----
    if (MODE == 0) {
        for (int i = tid; i < 64 * 36; i += 256) {
            int r = i / 36, c = i - r * 36;
            uint4 val;
            if (c < 16)      val = *(const uint4*)(hbf + (size_t)SIDX[r] * DH + c * 8);
            else if (c < 32) val = *(const uint4*)(hbf + (size_t)DIDX[r] * DH + (c - 16) * 8);
            else if (c < 34) {
                int e = row0 + r; if (e >= M) e = M - 1;
                val = *(const uint4*)(aux + (size_t)e * 16 + (c - 32) * 8);
            } else val = make_uint4(0, 0, 0, 0);
            *(uint4*)(A1 + r * K1P + c * 8) = val;
        }
    } else if (MODE == 1) {
        for (int i = tid; i < 64 * 32; i += 256) {
            int r = i >> 5, c = i & 31;
            int n = row0 + r; if (n >= M) n = M - 1;
            uint4 val;
            if (c < 16) val = *(const uint4*)(hbf + (size_t)n * DH + c * 8);
            else        val = *(const uint4*)(aux + (size_t)n * DH + (c - 16) * 8);
            *(uint4*)(A1 + r * K1P + c * 8) = val;
        }
    } else {
        for (int i = tid; i < 64 * 36; i += 256) {
            int r = i / 36, c = i - r * 36;
            uint4 val;
            if (c < 16)      val = *(const uint4*)(hbf + (size_t)SIDX[r] * DH + c * 8);
            else if (c < 32) val = *(const uint4*)(hbf + (size_t)DIDX[r] * DH + (c - 16) * 8);
            else if (c == 32) {
                int u = SIDX[r], v = DIDX[r];
                float ru = xyr[3 * u + 2], rv = xyr[3 * v + 2];
                float dx = xyr[3 * u] - xyr[3 * v];
                float dy = xyr[3 * u + 1] - xyr[3 * v + 1];
                float dist = sqrtf(dx * dx + dy * dy + 1e-8f);
                unsigned a0 = (unsigned)f2bf(ru) | ((unsigned)f2bf(rv) << 16);
                unsigned a1 = (unsigned)f2bf(dist) | ((unsigned)f2bf(fabsf(ru - rv)) << 16);
                val = make_uint4(a0, a1, 0, 0);
            } else val = make_uint4(0, 0, 0, 0);
            *(uint4*)(A1 + r * K1P + c * 8) = val;
        }
    }
    __syncthreads();

    const int lane = tid & 63;
    const int w = tid >> 6;        // wave id: cols [w*32, w*32+32)
    const int mr = lane & 15;
    const int q  = lane >> 4;

    // ---- GEMM1: A (LDS) x W1T (global) ----
    floatx4 acc[4][2] = {};
    for (int kc = 0; kc < KC1; ++kc) {
        const int ko = kc * 32 + q * 8;
        shortx8 a[4], bfr[2];
#pragma unroll
        for (int mt = 0; mt < 4; ++mt)
            a[mt] = *reinterpret_cast<const shortx8*>(A1 + (mt * 16 + mr) * K1P + ko);
#pragma unroll
        for (int nt = 0; nt < 2; ++nt)
            bfr[nt] = *reinterpret_cast<const shortx8*>(W1T + (size_t)(w * 32 + nt * 16 + mr) * K1B + ko);
#pragma unroll
        for (int mt = 0; mt < 4; ++mt)
#pragma unroll
            for (int nt = 0; nt < 2; ++nt)
                acc[mt][nt] = __builtin_amdgcn_mfma_f32_16x16x32_bf16(a[mt], bfr[nt], acc[mt][nt], 0, 0, 0);
    }

    // ---- epilogue1: bias + silu -> HID (bf16, A-layout rows) ----
#pragma unroll
    for (int nt = 0; nt < 2; ++nt) {
        int col = w * 32 + nt * 16 + mr;
        float bb = b1[col];
#pragma unroll
        for (int mt = 0; mt < 4; ++mt)
#pragma unroll
            for (int r = 0; r < 4; ++r) {
                int row = mt * 16 + q * 4 + r;
                HID[row * HP + col] = f2bf(silu_f(acc[mt][nt][r] + bb));
            }
    }
    __syncthreads();

    if (MODE == 2) {
        // logits: dot(hidden, eh_w2) + eh_b2
        if (tid < 64) {
            int p = row0 + tid;
            if (p < M) {
                float s = b2[0];
                for (int j = 0; j < DH; ++j) s += bf2f(HID[tid * HP + j]) * w2f[j];
                out_f[p] = s;
            }
        }
        return;
    }

    // ---- GEMM2: HID (LDS) x W2T (global) ----
    floatx4 acc2[4][2] = {};
    for (int kc = 0; kc < 4; ++kc) {
        const int ko = kc * 32 + q * 8;
        shortx8 a[4], bfr[2];
#pragma unroll
        for (int mt = 0; mt < 4; ++mt)
            a[mt] = *reinterpret_cast<const shortx8*>(HID + (mt * 16 + mr) * HP + ko);
#pragma unroll
        for (int nt = 0; nt < 2; ++nt)
            bfr[nt] = *reinterpret_cast<const shortx8*>(W2T + (size_t)(w * 32 + nt * 16 + mr) * DH + ko);
#pragma unroll
        for (int mt = 0; mt < 4; ++mt)
#pragma unroll
            for (int nt = 0; nt < 2; ++nt)
                acc2[mt][nt] = __builtin_amdgcn_mfma_f32_16x16x32_bf16(a[mt], bfr[nt], acc2[mt][nt], 0, 0, 0);
    }

    // ---- epilogue2 ----
#pragma unroll
    for (int nt = 0; nt < 2; ++nt) {
        int col = w * 32 + nt * 16 + mr;
        float bb = b2[col];
#pragma unroll
        for (int mt = 0; mt < 4; ++mt)
#pragma unroll
            for (int r = 0; r < 4; ++r) {
                int row = mt * 16 + q * 4 + r;
                int e = row0 + row;
                if (e < M) {
                    float xv = acc2[mt][nt][r] + bb;
                    if (MODE == 0) out_bf[(size_t)e * DH + col] = f2bf(xv);
                    else           out_f[(size_t)e * DH + col] = xv;
                }
            }
    }
}

extern "C" void kernel_launch(void* const* d_in, const int* in_sizes, int n_in,
                              void* d_out, int out_size, void* d_ws, size_t ws_size,
                              hipStream_t stream) {
    const float* xyr     = (const float*)d_in[0];
    const int*   eidx    = (const int*)d_in[1];
    const int*   pairs   = (const int*)d_in[2];
    const float* node_w1 = (const float*)d_in[3];
    const float* node_b1 = (const float*)d_in[4];
    const float* node_w2 = (const float*)d_in[5];
    const float* node_b2 = (const float*)d_in[6];
    const float* pm_w1   = (const float*)d_in[7];
    const float* pm_b1   = (const float*)d_in[8];
    const float* pm_w2   = (const float*)d_in[9];
    const float* pm_b2   = (const float*)d_in[10];
    const float* ph_w1   = (const float*)d_in[11];
    const float* ph_b1   = (const float*)d_in[12];
    const float* ph_w2   = (const float*)d_in[13];
    const float* ph_b2   = (const float*)d_in[14];
    const float* ln_g    = (const float*)d_in[15];
    const float* ln_b    = (const float*)d_in[16];
    const float* eh_w1   = (const float*)d_in[17];
    const float* eh_b1   = (const float*)d_in[18];
    const float* eh_w2   = (const float*)d_in[19];
    const float* eh_b2   = (const float*)d_in[20];

    const int N = in_sizes[0] / 3;
    const int E = in_sizes[1] / 2;
    const int P = in_sizes[2] / 2;
    const int* src = eidx;
    const int* dst = eidx + E;

    char* ws = (char*)d_ws;
    size_t off = 0;
    auto alloc = [&](size_t bytes) -> char* {
        char* p = ws + off;
        off += (bytes + 255) & ~(size_t)255;
        return p;
    };
    unsigned short* W1T   = (unsigned short*)alloc((size_t)3 * 128 * 288 * 2);
    unsigned short* W2T   = (unsigned short*)alloc((size_t)3 * 128 * 128 * 2);
    unsigned short* PH1T  = (unsigned short*)alloc((size_t)3 * 128 * 256 * 2);
    unsigned short* PH2T  = (unsigned short*)alloc((size_t)3 * 128 * 128 * 2);
    unsigned short* EH1T  = (unsigned short*)alloc((size_t)128 * 288 * 2);
    float*          h     = (float*)alloc((size_t)N * DH * 4);
    float*          hup   = (float*)alloc((size_t)N * DH * 4);
    unsigned short* hbf   = (unsigned short*)alloc((size_t)N * DH * 2);
    unsigned short* aggbf = (unsigned short*)alloc((size_t)N * DH * 2);
    unsigned short* rbfbf = (unsigned short*)alloc((size_t)E * 16 * 2);
    unsigned short* mbuf  = (unsigned short*)alloc((size_t)E * DH * 2);
    int*            cnt   = (int*)alloc((size_t)N * 4);
    int*            rs    = (int*)alloc((size_t)(N + 1) * 4);
    int*            cursor= (int*)alloc((size_t)N * 4);
    int*            eids  = (int*)alloc((size_t)E * 4);
    (void)ws_size; (void)n_in; (void)out_size;

    // weight prep
    prep_w_kernel<<<(3 * 128 * 288 + 255) / 256, 256, 0, stream>>>(pm_w1, W1T, 3, 272, 288);
    prep_w_kernel<<<(3 * 128 * 128 + 255) / 256, 256, 0, stream>>>(pm_w2, W2T, 3, 128, 128);
    prep_w_kernel<<<(3 * 128 * 256 + 255) / 256, 256, 0, stream>>>(ph_w1, PH1T, 3, 256, 256);
    prep_w_kernel<<<(3 * 128 * 128 + 255) / 256, 256, 0, stream>>>(ph_w2, PH2T, 3, 128, 128);
    prep_w_kernel<<<(1 * 128 * 288 + 255) / 256, 256, 0, stream>>>(eh_w1, EH1T, 1, 260, 288);

    // node encoder + rbf + CSR
    node_enc_kernel<<<(N + 15) / 16, 128, 0, stream>>>(xyr, node_w1, node_b1, node_w2, node_b2, h, hbf, N);
    rbf_kernel<<<(E + 255) / 256, 256, 0, stream>>>(xyr, src, dst, rbfbf, E);
    hipMemsetAsync(cnt, 0, (size_t)N * 4, stream);
    count_kernel<<<(E + 255) / 256, 256, 0, stream>>>(dst, cnt, E);
    scan_kernel<<<1, 1024, 0, stream>>>(cnt, rs, cursor, N);
    fill_kernel<<<(E + 255) / 256, 256, 0, stream>>>(dst, cursor, eids, E);

    // layers
    for (int l = 0; l < 3; ++l) {
        const unsigned short* w1t = W1T + (size_t)l * 128 * 288;
        const unsigned short* w2t = W2T + (size_t)l * 128 * 128;
        const unsigned short* p1t = PH1T + (size_t)l * 128 * 256;
        const unsigned short* p2t = PH2T + (size_t)l * 128 * 128;
        mlp2_kernel<0, 9><<<(E + 63) / 64, 256, 0, stream>>>(
            hbf, rbfbf, src, dst, nullptr, w1t, pm_b1 + l * DH, w2t, pm_b2 + l * DH,
            nullptr, mbuf, nullptr, E);
        agg_kernel<<<N, 128, 0, stream>>>(mbuf, rs, eids, aggbf, N);
        mlp2_kernel<1, 8><<<(N + 63) / 64, 256, 0, stream>>>(
            hbf, aggbf, nullptr, nullptr, nullptr, p1t, ph_b1 + l * DH, p2t, ph_b2 + l * DH,
            nullptr, nullptr, hup, N);
        ln_kernel<<<N, 128, 0, stream>>>(h, hup, ln_g + l * DH, ln_b + l * DH, hbf, N);
    }

    // pair head -> logits
    mlp2_kernel<2, 9><<<(P + 63) / 64, 256, 0, stream>>>(
        hbf, nullptr, pairs, nullptr, xyr, EH1T, eh_b1, nullptr, eh_b2,
        eh_w2, nullptr, (float*)d_out, P);
}

// Round 2
// 561.303 us; speedup vs baseline: 1.7485x; 1.7485x over previous
//
#include <hip/hip_runtime.h>

#define DH 128

typedef float  floatx4 __attribute__((ext_vector_type(4)));
typedef short  shortx8 __attribute__((ext_vector_type(8)));

__device__ __forceinline__ unsigned short f2bf(float f) {
    unsigned u = __builtin_bit_cast(unsigned, f);
    u += 0x7fffu + ((u >> 16) & 1u);
    return (unsigned short)(u >> 16);
}
__device__ __forceinline__ float bf2f(unsigned short h) {
    unsigned u = ((unsigned)h) << 16;
    return __builtin_bit_cast(float, u);
}
__device__ __forceinline__ float silu_f(float x) { return x / (1.f + expf(-x)); }

// ---- prep: split-concat transpose  dst[l][j][k] = src[l][(j>>7)*128+k][j&127], bf16, j<256,k<128 ----
__global__ void prep_split_kernel(const float* __restrict__ src, unsigned short* __restrict__ dst,
                                  int L, int SR) {
    int idx = blockIdx.x * 256 + threadIdx.x;
    int tot = L * 256 * 128;
    if (idx >= tot) return;
    int l = idx / (256 * 128);
    int rem = idx - l * 256 * 128;
    int j = rem >> 7;
    int k = rem & 127;
    int srow = ((j >> 7) << 7) + k;
    dst[idx] = f2bf(src[(size_t)l * SR * 128 + (size_t)srow * 128 + (j & 127)]);
}

// ---- prep: plain transpose  dst[l][j][k] = src[l][k][j], bf16, j<128,k<K ----
__global__ void prep_T_kernel(const float* __restrict__ src, unsigned short* __restrict__ dst,
                              int L, int K) {
    int idx = blockIdx.x * 256 + threadIdx.x;
    int tot = L * 128 * K;
    if (idx >= tot) return;
    int l = idx / (128 * K);
    int rem = idx - l * 128 * K;
    int j = rem / K;
    int k = rem - j * K;
    dst[idx] = f2bf(src[(size_t)l * K * 128 + (size_t)k * 128 + j]);
}

// ---- node encoder: h = silu(x@w1+b1)@w2+b2 ----
__global__ __launch_bounds__(128)
void node_enc_kernel(const float* __restrict__ xyr,
                     const float* __restrict__ w1, const float* __restrict__ b1,
                     const float* __restrict__ w2, const float* __restrict__ b2,
                     float* __restrict__ h, unsigned short* __restrict__ hbf, int N) {
    __shared__ float xs[16][3];
    __shared__ float hid[16][DH];
    int n0 = blockIdx.x * 16;
    int t = threadIdx.x;
    if (t < 48) {
        int i = t / 3, j = t - 3 * (t / 3);
        int n = n0 + i; if (n >= N) n = N - 1;
        xs[i][j] = xyr[3 * n + j];
    }
    __syncthreads();
    int col = t;
    float w10 = w1[col], w11 = w1[DH + col], w12 = w1[2 * DH + col];
    float bb = b1[col];
#pragma unroll
    for (int i = 0; i < 16; ++i) {
        float v = bb + xs[i][0] * w10 + xs[i][1] * w11 + xs[i][2] * w12;
        hid[i][col] = silu_f(v);
    }
    __syncthreads();
    float a[16];
#pragma unroll
    for (int i = 0; i < 16; ++i) a[i] = b2[col];
    for (int j = 0; j < DH; ++j) {
        float wv = w2[j * DH + col];
#pragma unroll
        for (int i = 0; i < 16; ++i) a[i] += hid[i][j] * wv;
    }
    for (int i = 0; i < 16; ++i) {
        int n = n0 + i;
        if (n < N) {
            h[(size_t)n * DH + col] = a[i];
            hbf[(size_t)n * DH + col] = f2bf(a[i]);
        }
    }
}

// ---- CSR build ----
__global__ void count_kernel(const int* __restrict__ dst, int* __restrict__ cnt, int E) {
    int e = blockIdx.x * 256 + threadIdx.x;
    if (e < E) atomicAdd(&cnt[dst[e]], 1);
}
__global__ __launch_bounds__(1024)
void scan_kernel(const int* __restrict__ cnt, int* __restrict__ rs, int* __restrict__ cursor,
                 float* __restrict__ cntf, int N) {
    __shared__ int ps[1024];
    const int CH = 16;
    int t = threadIdx.x;
    int base = t * CH;
    int loc[CH];
    int s = 0;
#pragma unroll
    for (int j = 0; j < CH; ++j) {
        int i = base + j;
        int v = (i < N) ? cnt[i] : 0;
        if (i < N) cntf[i] = (float)v;
        loc[j] = s; s += v;
    }
    ps[t] = s;
    __syncthreads();
    for (int off = 1; off < 1024; off <<= 1) {
        int v = (t >= off) ? ps[t - off] : 0;
        __syncthreads();
        ps[t] += v;
        __syncthreads();
    }
    int pre = (t > 0) ? ps[t - 1] : 0;
#pragma unroll
    for (int j = 0; j < CH; ++j) {
        int i = base + j;
        if (i < N) { int v = pre + loc[j]; rs[i] = v; cursor[i] = v; }
    }
    if (t == 0) rs[N] = ps[1023];
}
__global__ void fill_kernel(const int* __restrict__ dst, int* __restrict__ cursor,
                            int* __restrict__ eids, int E) {
    int e = blockIdx.x * 256 + threadIdx.x;
    if (e < E) {
        int p = atomicAdd(&cursor[dst[e]], 1);
        eids[p] = e;
    }
}
// ---- per-CSR-slot: src node + fp32 rbf ----
__global__ void edgeprep_kernel(const int* __restrict__ src, const int* __restrict__ dst,
                                const int* __restrict__ eids, const float* __restrict__ xyr,
                                int* __restrict__ esrc, float* __restrict__ rbfc, int E) {
    int j = blockIdx.x * 256 + threadIdx.x;
    if (j >= E) return;
    int e = eids[j];
    int s = src[e], d = dst[e];
    esrc[j] = s;
    float dx = xyr[3 * s] - xyr[3 * d];
    float dy = xyr[3 * s + 1] - xyr[3 * d + 1];
    float r = sqrtf(dx * dx + dy * dy + 1e-8f);
    const float step = 1.41421356237309515f / 15.f;
    const float gamma = 56.25f;
#pragma unroll
    for (int k = 0; k < 16; ++k) {
        float dd = r - k * step;
        rbfc[(size_t)j * 16 + k] = expf(-gamma * dd * dd);
    }
}

// ---- proj: O1||O2 = Abf @ BT^T  (M x 128 @ 128 x 256), fp32 out, no bias ----
__global__ __launch_bounds__(256)
void proj_kernel(const unsigned short* __restrict__ Abf,
                 const unsigned short* __restrict__ BT,   // [256][128] bf16
                 float* __restrict__ O1, float* __restrict__ O2, int M) {
    const int tid = threadIdx.x;
    const int w = tid >> 6, lane = tid & 63;
    const int mr = lane & 15, q = lane >> 4;
    const int row0 = blockIdx.x * 64;
    floatx4 acc[4][4] = {};
#pragma unroll
    for (int kc = 0; kc < 4; ++kc) {
        const int ko = kc * 32 + q * 8;
        shortx8 a[4], b[4];
#pragma unroll
        for (int mt = 0; mt < 4; ++mt) {
            int r = row0 + mt * 16 + mr; if (r >= M) r = M - 1;
            a[mt] = *reinterpret_cast<const shortx8*>(Abf + (size_t)r * DH + ko);
        }
#pragma unroll
        for (int nt = 0; nt < 4; ++nt) {
            int ocol = w * 64 + nt * 16 + mr;
            b[nt] = *reinterpret_cast<const shortx8*>(BT + (size_t)ocol * DH + ko);
        }
#pragma unroll
        for (int mt = 0; mt < 4; ++mt)
#pragma unroll
            for (int nt = 0; nt < 4; ++nt)
                acc[mt][nt] = __builtin_amdgcn_mfma_f32_16x16x32_bf16(a[mt], b[nt], acc[mt][nt], 0, 0, 0);
    }
#pragma unroll
    for (int nt = 0; nt < 4; ++nt) {
        int ocol = w * 64 + nt * 16 + mr;
        float* O = (ocol < DH) ? O1 : O2;
        int col = ocol & (DH - 1);
#pragma unroll
        for (int mt = 0; mt < 4; ++mt)
#pragma unroll
            for (int r4 = 0; r4 < 4; ++r4) {
                int gr = row0 + mt * 16 + q * 4 + r4;
                if (gr < M) O[(size_t)gr * DH + col] = acc[mt][nt][r4];
            }
    }
}

// ---- edge stream + aggregate: S[n] = sum_{e:dst=n} silu(Hs[src]+Hd[n]+b1+rbf@W1c), fp32 ----
__global__ __launch_bounds__(128)
void edge_kernel(const float* __restrict__ Hs, const float* __restrict__ Hd,
                 const float* __restrict__ w1c,   // [16][128] fp32 (pm_w1 rows 256..271)
                 const float* __restrict__ b1,
                 const int* __restrict__ rs, const int* __restrict__ esrc,
                 const float* __restrict__ rbfc,
                 float* __restrict__ S, int N) {
    int n = blockIdx.x, c = threadIdx.x;
    float wc[16];
#pragma unroll
    for (int k = 0; k < 16; ++k) wc[k] = w1c[k * DH + c];
    float hdn = Hd[(size_t)n * DH + c] + b1[c];
    int s = rs[n], e = rs[n + 1];
    float acc = 0.f;
#pragma unroll 2
    for (int j = s; j < e; ++j) {
        int sn = esrc[j];
        float hs = Hs[(size_t)sn * DH + c];
        const float4* rp = (const float4*)(rbfc + (size_t)j * 16);
        float4 r0 = rp[0], r1 = rp[1], r2 = rp[2], r3 = rp[3];
        float pre = hs + hdn;
        pre += r0.x * wc[0] + r0.y * wc[1] + r0.z * wc[2] + r0.w * wc[3];
        pre += r1.x * wc[4] + r1.y * wc[5] + r1.z * wc[6] + r1.w * wc[7];
        pre += r2.x * wc[8] + r2.y * wc[9] + r2.z * wc[10] + r2.w * wc[11];
        pre += r3.x * wc[12] + r3.y * wc[13] + r3.z * wc[14] + r3.w * wc[15];
        acc += silu_f(pre);
    }
    S[(size_t)n * DH + c] = acc;
}

// ---- agg = S @ W2 + cnt*b2 (fp32 VALU), out bf16 ----
__global__ __launch_bounds__(128)
void aggw2_kernel(const float* __restrict__ S, const float* __restrict__ W2,
                  const float* __restrict__ b2, const float* __restrict__ cntf,
                  unsigned short* __restrict__ aggbf, int N) {
    __shared__ float Ssh[16][DH];
    int n0 = blockIdx.x * 16, c = threadIdx.x;
    for (int i = c; i < 16 * DH; i += 128) {
        int r = i >> 7, k = i & 127;
        int n = n0 + r;
        Ssh[r][k] = (n < N) ? S[(size_t)n * DH + k] : 0.f;
    }
    __syncthreads();
    float acc[16];
#pragma unroll
    for (int r = 0; r < 16; ++r) acc[r] = 0.f;
    for (int k = 0; k < DH; ++k) {
        float wv = W2[(size_t)k * DH + c];
#pragma unroll
        for (int r = 0; r < 16; ++r) acc[r] += Ssh[r][k] * wv;
    }
    float b2c = b2[c];
#pragma unroll
    for (int r = 0; r < 16; ++r) {
        int n = n0 + r;
        if (n < N) aggbf[(size_t)n * DH + c] = f2bf(acc[r] + cntf[n] * b2c);
    }
}

// ---- node update: h_up = mlp2([h|agg]) ; h = LN(h + h_up) ; fused ----
__global__ __launch_bounds__(256)
void upd_kernel(unsigned short* hbf,                       // in (GEMM rows) + out (post-LN)
                const unsigned short* __restrict__ aggbf,
                float* h,                                   // in residual + out
                const unsigned short* __restrict__ P1T,    // [128][256]
                const float* __restrict__ b1v,
                const unsigned short* __restrict__ P2T,    // [128][128]
                const float* __restrict__ b2v,
                const float* __restrict__ g, const float* __restrict__ bb,
                int M) {
    __shared__ unsigned short HID[64 * 136];
    __shared__ float red[4][64][2];
    __shared__ float stats[64][2];
    const int tid = threadIdx.x;
    const int w = tid >> 6, lane = tid & 63;
    const int mr = lane & 15, q = lane >> 4;
    const int row0 = blockIdx.x * 64;

    // GEMM2: [hbf | aggbf] (K=256) @ P1T -> silu -> HID
    floatx4 acc[4][2] = {};
#pragma unroll
    for (int kc = 0; kc < 8; ++kc) {
        const int ko = kc * 32 + q * 8;
        shortx8 a[4], bfr[2];
#pragma unroll
        for (int mt = 0; mt < 4; ++mt) {
            int r = row0 + mt * 16 + mr; if (r >= M) r = M - 1;
            const unsigned short* sp = (ko < DH) ? (hbf + (size_t)r * DH + ko)
                                                 : (aggbf + (size_t)r * DH + (ko - DH));
            a[mt] = *reinterpret_cast<const shortx8*>(sp);
        }
#pragma unroll
        for (int nt = 0; nt < 2; ++nt)
            bfr[nt] = *reinterpret_cast<const shortx8*>(P1T + (size_t)(w * 32 + nt * 16 + mr) * 256 + ko);
#pragma unroll
        for (int mt = 0; mt < 4; ++mt)
#pragma unroll
            for (int nt = 0; nt < 2; ++nt)
                acc[mt][nt] = __builtin_amdgcn_mfma_f32_16x16x32_bf16(a[mt], bfr[nt], acc[mt][nt], 0, 0, 0);
    }
#pragma unroll
    for (int nt = 0; nt < 2; ++nt) {
        int col = w * 32 + nt * 16 + mr;
        float bv = b1v[col];
#pragma unroll
        for (int mt = 0; mt < 4; ++mt)
#pragma unroll
            for (int r4 = 0; r4 < 4; ++r4) {
                int row = mt * 16 + q * 4 + r4;
                HID[row * 136 + col] = f2bf(silu_f(acc[mt][nt][r4] + bv));
            }
    }
    __syncthreads();

    // GEMM3: HID (K=128) @ P2T -> + b2 + h (residual) kept in regs
    floatx4 acc3[4][2] = {};
#pragma unroll
    for (int kc = 0; kc < 4; ++kc) {
        const int ko = kc * 32 + q * 8;
        shortx8 a[4], bfr[2];
#pragma unroll
        for (int mt = 0; mt < 4; ++mt)
            a[mt] = *reinterpret_cast<const shortx8*>(HID + (mt * 16 + mr) * 136 + ko);
#pragma unroll
        for (int nt = 0; nt < 2; ++nt)
            bfr[nt] = *reinterpret_cast<const shortx8*>(P2T + (size_t)(w * 32 + nt * 16 + mr) * DH + ko);
#pragma unroll
        for (int mt = 0; mt < 4; ++mt)
#pragma unroll
            for (int nt = 0; nt < 2; ++nt)
                acc3[mt][nt] = __builtin_amdgcn_mfma_f32_16x16x32_bf16(a[mt], bfr[nt], acc3[mt][nt], 0, 0, 0);
    }
#pragma unroll
    for (int nt = 0; nt < 2; ++nt) {
        int col = w * 32 + nt * 16 + mr;
        float b2c = b2v[col];
#pragma unroll
        for (int mt = 0; mt < 4; ++mt)
#pragma unroll
            for (int r4 = 0; r4 < 4; ++r4) {
                int gr = row0 + mt * 16 + q * 4 + r4;
                float hv = (gr < M) ? h[(size_t)gr * DH + col] : 0.f;
                acc3[mt][nt][r4] = acc3[mt][nt][r4] + b2c + hv;   // y
            }
    }
    // LN: row sums (wave partial over its 32 cols, then cross-wave via LDS)
#pragma unroll
    for (int mt = 0; mt < 4; ++mt)
#pragma unroll
        for (int r4 = 0; r4 < 4; ++r4) {
            float y0 = acc3[mt][0][r4], y1 = acc3[mt][1][r4];
            float s1 = y0 + y1, s2 = y0 * y0 + y1 * y1;
#pragma unroll
            for (int m = 1; m < 16; m <<= 1) {
                s1 += __shfl_xor(s1, m);
                s2 += __shfl_xor(s2, m);
            }
            if (mr == 0) {
                int row = mt * 16 + q * 4 + r4;
                red[w][row][0] = s1; red[w][row][1] = s2;
            }
        }
    __syncthreads();
    if (tid < 64) {
        float s1 = red[0][tid][0] + red[1][tid][0] + red[2][tid][0] + red[3][tid][0];
        float s2 = red[0][tid][1] + red[1][tid][1] + red[2][tid][1] + red[3][tid][1];
        float mu = s1 * (1.f / DH);
        float var = s2 * (1.f / DH) - mu * mu;
        stats[tid][0] = mu;
        stats[tid][1] = rsqrtf(var + 1e-5f);
    }
    __syncthreads();
#pragma unroll
    for (int nt = 0; nt < 2; ++nt) {
        int col = w * 32 + nt * 16 + mr;
        float gc = g[col], bc = bb[col];
#pragma unroll
        for (int mt = 0; mt < 4; ++mt)
#pragma unroll
            for (int r4 = 0; r4 < 4; ++r4) {
                int row = mt * 16 + q * 4 + r4;
                int gr = row0 + row;
                if (gr < M) {
                    float yv = (acc3[mt][nt][r4] - stats[row][0]) * stats[row][1] * gc + bc;
                    h[(size_t)gr * DH + col] = yv;
                    hbf[(size_t)gr * DH + col] = f2bf(yv);
                }
            }
    }
}

// ---- pair head: logit = silu(Hu[u]+Hv[v]+b1+rp@W1c) . w2 + b2 ; one wave per pair ----
__global__ __launch_bounds__(256)
void pair_kernel(const float* __restrict__ Hu, const float* __restrict__ Hv,
                 const int* __restrict__ pairs, const float* __restrict__ xyr,
                 const float* __restrict__ ehw1c,   // [4][128] fp32 (eh_w1 rows 256..259)
                 const float* __restrict__ eb1, const float* __restrict__ ew2,
                 const float* __restrict__ eb2,
                 float* __restrict__ out, int P) {
    int w = threadIdx.x >> 6, lane = threadIdx.x & 63;
    int p = blockIdx.x * 4 + w;
    if (p >= P) return;
    int u = pairs[2 * p], v = pairs[2 * p + 1];
    float ru = xyr[3 * u + 2], rv = xyr[3 * v + 2];
    float dx = xyr[3 * u] - xyr[3 * v];
    float dy = xyr[3 * u + 1] - xyr[3 * v + 1];
    float dist = sqrtf(dx * dx + dy * dy + 1e-8f);
    float adr = fabsf(ru - rv);
    int c = lane * 2;
    float2 hu = *(const float2*)(Hu + (size_t)u * DH + c);
    float2 hv = *(const float2*)(Hv + (size_t)v * DH + c);
    float2 bv = *(const float2*)(eb1 + c);
    float2 wv = *(const float2*)(ew2 + c);
    float2 c0 = *(const float2*)(ehw1c + 0 * DH + c);
    float2 c1 = *(const float2*)(ehw1c + 1 * DH + c);
    float2 c2 = *(const float2*)(ehw1c + 2 * DH + c);
    float2 c3 = *(const float2*)(ehw1c + 3 * DH + c);
    float px = hu.x + hv.x + bv.x + ru * c0.x + rv * c1.x + dist * c2.x + adr * c3.x;
    float py = hu.y + hv.y + bv.y + ru * c0.y + rv * c1.y + dist * c2.y + adr * c3.y;
    float val = silu_f(px) * wv.x + silu_f(py) * wv.y;
#pragma unroll
    for (int m = 1; m < 64; m <<= 1) val += __shfl_xor(val, m);
    if (lane == 0) out[p] = val + eb2[0];
}

extern "C" void kernel_launch(void* const* d_in, const int* in_sizes, int n_in,
                              void* d_out, int out_size, void* d_ws, size_t ws_size,
                              hipStream_t stream) {
    const float* xyr     = (const float*)d_in[0];
    const int*   eidx    = (const int*)d_in[1];
    const int*   pairs   = (const int*)d_in[2];
    const float* node_w1 = (const float*)d_in[3];
    const float* node_b1 = (const float*)d_in[4];
    const float* node_w2 = (const float*)d_in[5];
    const float* node_b2 = (const float*)d_in[6];
    const float* pm_w1   = (const float*)d_in[7];
    const float* pm_b1   = (const float*)d_in[8];
    const float* pm_w2   = (const float*)d_in[9];
    const float* pm_b2   = (const float*)d_in[10];
    const float* ph_w1   = (const float*)d_in[11];
    const float* ph_b1   = (const float*)d_in[12];
    const float* ph_w2   = (const float*)d_in[13];
    const float* ph_b2   = (const float*)d_in[14];
    const float* ln_g    = (const float*)d_in[15];
    const float* ln_b    = (const float*)d_in[16];
    const float* eh_w1   = (const float*)d_in[17];
    const float* eh_b1   = (const float*)d_in[18];
    const float* eh_w2   = (const float*)d_in[19];
    const float* eh_b2   = (const float*)d_in[20];

    const int N = in_sizes[0] / 3;
    const int E = in_sizes[1] / 2;
    const int P = in_sizes[2] / 2;
    const int* src = eidx;
    const int* dst = eidx + E;

    char* ws = (char*)d_ws;
    size_t off = 0;
    auto alloc = [&](size_t bytes) -> char* {
        char* p = ws + off;
        off += (bytes + 255) & ~(size_t)255;
        return p;
    };
    unsigned short* W1abT = (unsigned short*)alloc((size_t)3 * 256 * 128 * 2);
    unsigned short* PH1T  = (unsigned short*)alloc((size_t)3 * 128 * 256 * 2);
    unsigned short* PH2T  = (unsigned short*)alloc((size_t)3 * 128 * 128 * 2);
    unsigned short* EHT   = (unsigned short*)alloc((size_t)256 * 128 * 2);
    float*          h     = (float*)alloc((size_t)N * DH * 4);
    unsigned short* hbf   = (unsigned short*)alloc((size_t)N * DH * 2);
    float*          Hs    = (float*)alloc((size_t)N * DH * 4);
    float*          Hd    = (float*)alloc((size_t)N * DH * 4);
    float*          S     = (float*)alloc((size_t)N * DH * 4);
    unsigned short* aggbf = (unsigned short*)alloc((size_t)N * DH * 2);
    float*          rbfc  = (float*)alloc((size_t)E * 16 * 4);
    int*            esrc  = (int*)alloc((size_t)E * 4);
    int*            cnt   = (int*)alloc((size_t)N * 4);
    int*            rs    = (int*)alloc((size_t)(N + 1) * 4);
    int*            cursor= (int*)alloc((size_t)N * 4);
    float*          cntf  = (float*)alloc((size_t)N * 4);
    int*            eids  = (int*)alloc((size_t)E * 4);
    (void)ws_size; (void)n_in; (void)out_size;

    // weight prep
    prep_split_kernel<<<(3 * 256 * 128 + 255) / 256, 256, 0, stream>>>(pm_w1, W1abT, 3, 272);
    prep_split_kernel<<<(256 * 128 + 255) / 256, 256, 0, stream>>>(eh_w1, EHT, 1, 260);
    prep_T_kernel<<<(3 * 128 * 256 + 255) / 256, 256, 0, stream>>>(ph_w1, PH1T, 3, 256);
    prep_T_kernel<<<(3 * 128 * 128 + 255) / 256, 256, 0, stream>>>(ph_w2, PH2T, 3, 128);

    // node encoder + CSR + per-slot edge data
    node_enc_kernel<<<(N + 15) / 16, 128, 0, stream>>>(xyr, node_w1, node_b1, node_w2, node_b2, h, hbf, N);
    hipMemsetAsync(cnt, 0, (size_t)N * 4, stream);
    count_kernel<<<(E + 255) / 256, 256, 0, stream>>>(dst, cnt, E);
    scan_kernel<<<1, 1024, 0, stream>>>(cnt, rs, cursor, cntf, N);
    fill_kernel<<<(E + 255) / 256, 256, 0, stream>>>(dst, cursor, eids, E);
    edgeprep_kernel<<<(E + 255) / 256, 256, 0, stream>>>(src, dst, eids, xyr, esrc, rbfc, E);

    const int MB = (N + 63) / 64;
    for (int l = 0; l < 3; ++l) {
        proj_kernel<<<MB, 256, 0, stream>>>(hbf, W1abT + (size_t)l * 256 * 128, Hs, Hd, N);
        edge_kernel<<<N, 128, 0, stream>>>(Hs, Hd, pm_w1 + (size_t)l * 272 * 128 + 256 * 128,
                                           pm_b1 + l * DH, rs, esrc, rbfc, S, N);
        aggw2_kernel<<<(N + 15) / 16, 128, 0, stream>>>(S, pm_w2 + (size_t)l * 128 * 128,
                                                        pm_b2 + l * DH, cntf, aggbf, N);
        upd_kernel<<<MB, 256, 0, stream>>>(hbf, aggbf, h,
                                           PH1T + (size_t)l * 128 * 256, ph_b1 + l * DH,
                                           PH2T + (size_t)l * 128 * 128, ph_b2 + l * DH,
                                           ln_g + l * DH, ln_b + l * DH, N);
    }

    // pair head: reuse Hs/Hd as Hu/Hv
    proj_kernel<<<MB, 256, 0, stream>>>(hbf, EHT, Hs, Hd, N);
    pair_kernel<<<(P + 3) / 4, 256, 0, stream>>>(Hs, Hd, pairs, xyr, eh_w1 + 256 * DH,
                                                 eh_b1, eh_w2, eh_b2, (float*)d_out, P);
}